// Round 6
// baseline (104.993 us; speedup 1.0000x reference)
//
#include <hip/hip_runtime.h>
#include <math.h>

// B=4096 batches, C=128 classes.
//   p = softmax(mu[b])
//   sigma_y[i,l] = p_i p_l (sigma[i,l] - r[l] - c[i] + s)
//   r = p^T sigma, c = sigma p, s = p^T sigma p
// Streaming memory-bound. TPB=512, KIT=8, one batch/block, grid=8192.
// Target <=64 VGPR -> 4 blocks/CU (32 waves) for 4-way phase interleave.

#define C_DIM   128
#define TPB     512
#define F4_PB   4096        // C*C/4 float4 per batch
#define KIT     8           // F4_PB / TPB

typedef float f4 __attribute__((ext_vector_type(4)));

__global__ __launch_bounds__(TPB, 8) void vdp_softmax_kernel(
    const float* __restrict__ mu,
    const float* __restrict__ sigma,
    float* __restrict__ out_p,
    float* __restrict__ out_sy)
{
    const int b    = blockIdx.x;
    const int t    = threadIdx.x;
    const int lane = t & 63;
    const int wave = t >> 6;    // 0..7
    const int colg = t & 31;    // columns 4*colg .. 4*colg+3
    const int rowg = t >> 5;    // 0..15; rows rowg + 16k, k=0..7

    __shared__ float lds_p[C_DIM];
    __shared__ float lds_c[C_DIM];
    __shared__ float lds_r[C_DIM];
    __shared__ float lds_rpart[8][C_DIM];
    __shared__ float lds_red;

    // ---- mu first (softmax critical path), then sigma stream ----
    float x0 = 0.f, x1 = 0.f;
    if (wave == 0) {
        x0 = mu[(size_t)b * C_DIM + lane];
        x1 = mu[(size_t)b * C_DIM + 64 + lane];
    }
    const f4* sig4 = (const f4*)sigma + (size_t)b * F4_PB;
    f4 v[KIT];
#pragma unroll
    for (int k = 0; k < KIT; ++k)
        v[k] = __builtin_nontemporal_load(&sig4[t + TPB * k]);

    // ---- softmax on wave 0: 2 elems/lane, shuffle-only ----
    if (wave == 0) {
        float m = fmaxf(x0, x1);
#pragma unroll
        for (int off = 32; off >= 1; off >>= 1)
            m = fmaxf(m, __shfl_xor(m, off, 64));
        const float e0 = expf(x0 - m), e1 = expf(x1 - m);
        float ss = e0 + e1;
#pragma unroll
        for (int off = 32; off >= 1; off >>= 1)
            ss += __shfl_xor(ss, off, 64);
        const float inv = 1.0f / ss;
        const float p0 = e0 * inv, p1 = e1 * inv;
        lds_p[lane] = p0;
        lds_p[64 + lane] = p1;
        out_p[(size_t)b * C_DIM + lane] = p0;
        out_p[(size_t)b * C_DIM + 64 + lane] = p1;
    }
    __syncthreads();                                     // B1: p visible

    // ---- partial r (per-column, p-weighted) and c (per-row dot) ----
    const f4 pcol = *(const f4*)&lds_p[4 * colg];
    f4 pr = (f4)(0.f);
    float pc[KIT];
#pragma unroll
    for (int k = 0; k < KIT; ++k) {
        const float prow = lds_p[rowg + 16 * k];   // broadcast per half-wave
        const f4 vk = v[k];
        pr += prow * vk;
        pc[k] = vk.x * pcol.x + vk.y * pcol.y + vk.z * pcol.z + vk.w * pcol.w;
    }

    // r: lanes l and l+32 share colg -> combine, then 8 wave partials
    pr.x += __shfl_xor(pr.x, 32, 64);
    pr.y += __shfl_xor(pr.y, 32, 64);
    pr.z += __shfl_xor(pr.z, 32, 64);
    pr.w += __shfl_xor(pr.w, 32, 64);
    if (lane < 32)
        *(f4*)&lds_rpart[wave][4 * colg] = pr;

    // c: each half-wave owns one rowg; reduce its 32 column groups
#pragma unroll
    for (int off = 1; off <= 16; off <<= 1) {
#pragma unroll
        for (int k = 0; k < KIT; ++k)
            pc[k] += __shfl_xor(pc[k], off, 64);
    }
    if ((lane & 31) == 0) {
#pragma unroll
        for (int k = 0; k < KIT; ++k)
            lds_c[rowg + 16 * k] = pc[k];          // each row written once
    }
    __syncthreads();                                     // B2: rpart, c visible

    // ---- finalize r (128 threads); s = p.c (wave 1) ----
    if (t < C_DIM) {
        float rsum = 0.f;
#pragma unroll
        for (int w = 0; w < 8; ++w)
            rsum += lds_rpart[w][t];
        lds_r[t] = rsum;
    }
    if (wave == 1) {
        float sv = lds_p[lane] * lds_c[lane] + lds_p[64 + lane] * lds_c[64 + lane];
#pragma unroll
        for (int off = 32; off >= 1; off >>= 1)
            sv += __shfl_xor(sv, off, 64);
        if (lane == 0) lds_red = sv;
    }
    __syncthreads();                                     // B3: r, s visible

    // ---- output ----
    const f4 r4 = *(const f4*)&lds_r[4 * colg];
    const float s = lds_red;
    f4* out4 = (f4*)out_sy + (size_t)b * F4_PB;
#pragma unroll
    for (int k = 0; k < KIT; ++k) {
        const int row = rowg + 16 * k;
        const float pp   = lds_p[row];
        const float base = s - lds_c[row];
        const f4 vk = v[k];
        f4 o;
        o.x = pp * pcol.x * (vk.x - r4.x + base);
        o.y = pp * pcol.y * (vk.y - r4.y + base);
        o.z = pp * pcol.z * (vk.z - r4.z + base);
        o.w = pp * pcol.w * (vk.w - r4.w + base);
        __builtin_nontemporal_store(o, &out4[t + TPB * k]);
    }
}

extern "C" void kernel_launch(void* const* d_in, const int* in_sizes, int n_in,
                              void* d_out, int out_size, void* d_ws, size_t ws_size,
                              hipStream_t stream) {
    const float* mu    = (const float*)d_in[0];
    const float* sigma = (const float*)d_in[1];
    float* out_p  = (float*)d_out;                  // [B, C]
    const int B = in_sizes[0] / C_DIM;              // 4096
    float* out_sy = out_p + (size_t)B * C_DIM;      // [B, C, C]

    vdp_softmax_kernel<<<B, TPB, 0, stream>>>(mu, sigma, out_p, out_sy);
}

// Round 7
// 93.839 us; speedup vs baseline: 1.1189x; 1.1189x over previous
//
#include <hip/hip_runtime.h>
#include <math.h>

// B=4096 batches, C=128 classes.
//   p = softmax(mu[b])
//   sigma_y[i,l] = p_i p_l (sigma[i,l] - r[l] - c[i] + s)
//   r = p^T sigma, c = sigma p, s = p^T sigma p
// Streaming memory-bound: sigma read once into registers, sigma_y written once.
// Best measured config (R3, 91.45 us = 5.87 TB/s effective, 94% of the
// 6.29 TB/s measured copy ceiling): TPB=1024, KIT=4, <=64 VGPR -> 2 blocks/CU.
// Measured and rejected: persistent pipelined blocks (97.9), 3-barrier
// variant (93.3), TPB=512/KIT=8 4-block interleave (105.0).

#define C_DIM   128
#define TPB     1024
#define F4_PB   4096        // C*C/4 float4 per batch
#define KIT     4           // F4_PB / TPB

typedef float f4 __attribute__((ext_vector_type(4)));   // nontemporal-compatible

__global__ __launch_bounds__(TPB, 8) void vdp_softmax_kernel(
    const float* __restrict__ mu,
    const float* __restrict__ sigma,
    float* __restrict__ out_p,
    float* __restrict__ out_sy)
{
    const int b    = blockIdx.x;
    const int t    = threadIdx.x;
    const int lane = t & 63;
    const int wave = t >> 6;    // 0..15
    const int colg = t & 31;    // columns 4*colg .. 4*colg+3
    const int rowg = t >> 5;    // 0..31; rows rowg + 32k, k=0..3

    __shared__ float lds_p[C_DIM];
    __shared__ float lds_c[C_DIM];
    __shared__ float lds_r[C_DIM];
    __shared__ float lds_rpart[16][C_DIM];
    __shared__ float lds_red[4];

    // ---- issue all sigma loads early (independent of softmax) ----
    const f4* sig4 = (const f4*)sigma + (size_t)b * F4_PB;
    f4 v[KIT];
#pragma unroll
    for (int k = 0; k < KIT; ++k)
        v[k] = __builtin_nontemporal_load(&sig4[t + TPB * k]);

    // ---- softmax over mu[b, 0:128] on waves 0,1 ----
    float x = 0.f, e = 0.f;
    if (wave < 2) {
        x = mu[(size_t)b * C_DIM + t];
        float m = x;
#pragma unroll
        for (int off = 32; off >= 1; off >>= 1)
            m = fmaxf(m, __shfl_xor(m, off, 64));
        if (lane == 0) lds_red[wave] = m;
    }
    __syncthreads();
    if (wave < 2) {
        const float gmax = fmaxf(lds_red[0], lds_red[1]);
        e = expf(x - gmax);
        float ssum = e;
#pragma unroll
        for (int off = 32; off >= 1; off >>= 1)
            ssum += __shfl_xor(ssum, off, 64);
        if (lane == 0) lds_red[2 + wave] = ssum;
    }
    __syncthreads();
    if (wave < 2) {
        const float pv = e / (lds_red[2] + lds_red[3]);
        lds_p[t] = pv;
        out_p[(size_t)b * C_DIM + t] = pv;
    }
    __syncthreads();

    const f4 pcol = *(const f4*)&lds_p[4 * colg];

    // ---- partial r (per-column, p-weighted) and c (per-row dot) ----
    f4 pr = (f4)(0.f);
    float pc[KIT];
#pragma unroll
    for (int k = 0; k < KIT; ++k) {
        const float prow = lds_p[rowg + 32 * k];   // broadcast per half-wave
        const f4 vk = v[k];
        pr += prow * vk;
        pc[k] = vk.x * pcol.x + vk.y * pcol.y + vk.z * pcol.z + vk.w * pcol.w;
    }

    // r: lanes l and l+32 share colg (rowg pair) -> combine, then 16 wave partials
    pr.x += __shfl_xor(pr.x, 32, 64);
    pr.y += __shfl_xor(pr.y, 32, 64);
    pr.z += __shfl_xor(pr.z, 32, 64);
    pr.w += __shfl_xor(pr.w, 32, 64);
    if (lane < 32)
        *(f4*)&lds_rpart[wave][4 * colg] = pr;

    // c: each half-wave owns one rowg; reduce its 32 column groups
#pragma unroll
    for (int off = 1; off <= 16; off <<= 1) {
#pragma unroll
        for (int k = 0; k < KIT; ++k)
            pc[k] += __shfl_xor(pc[k], off, 64);
    }
    if ((lane & 31) == 0) {
#pragma unroll
        for (int k = 0; k < KIT; ++k)
            lds_c[rowg + 32 * k] = pc[k];   // each row written exactly once
    }
    __syncthreads();

    if (t < C_DIM) {
        float rsum = 0.f;
#pragma unroll
        for (int w = 0; w < 16; ++w)
            rsum += lds_rpart[w][t];
        lds_r[t] = rsum;
    }

    // ---- s = sum_i p_i c_i (waves 0,1) ----
    float sval = (t < C_DIM) ? lds_p[t] * lds_c[t] : 0.f;
    if (wave < 2) {
#pragma unroll
        for (int off = 32; off >= 1; off >>= 1)
            sval += __shfl_xor(sval, off, 64);
        if (lane == 0) lds_red[wave] = sval;
    }
    __syncthreads();
    const float s = lds_red[0] + lds_red[1];

    // ---- output ----
    const f4 r4 = *(const f4*)&lds_r[4 * colg];
    f4* out4 = (f4*)out_sy + (size_t)b * F4_PB;
#pragma unroll
    for (int k = 0; k < KIT; ++k) {
        const int row = rowg + 32 * k;
        const float pp   = lds_p[row];
        const float base = s - lds_c[row];
        const f4 vk = v[k];
        f4 o;
        o.x = pp * pcol.x * (vk.x - r4.x + base);
        o.y = pp * pcol.y * (vk.y - r4.y + base);
        o.z = pp * pcol.z * (vk.z - r4.z + base);
        o.w = pp * pcol.w * (vk.w - r4.w + base);
        __builtin_nontemporal_store(o, &out4[t + TPB * k]);
    }
}

extern "C" void kernel_launch(void* const* d_in, const int* in_sizes, int n_in,
                              void* d_out, int out_size, void* d_ws, size_t ws_size,
                              hipStream_t stream) {
    const float* mu    = (const float*)d_in[0];
    const float* sigma = (const float*)d_in[1];
    float* out_p  = (float*)d_out;                  // [B, C]
    const int B = in_sizes[0] / C_DIM;              // 4096
    float* out_sy = out_p + (size_t)B * C_DIM;      // [B, C, C]

    vdp_softmax_kernel<<<B, TPB, 0, stream>>>(mu, sigma, out_p, out_sy);
}